// Round 12
// baseline (5525.355 us; speedup 1.0000x reference)
//
#include <hip/hip_runtime.h>
#include <hip/hip_bf16.h>

// ---------------------------------------------------------------------------
// LSTM_66675072303478: 2-layer LSTM (B=512,S=128,E=7,H=1024) + FC(1024->672)
//
// v23 = LDS-minimal assembly of individually-PROVEN components:
//  - Diagnosis (v22 post-mortem arithmetic): v15..v21 issue ~4600 LDS b128
//    wave-ops/CU/round ~= 55k cyc ~= the 22us round time -> LDS-throughput-
//    bound. MFMA is only ~2-3us/round. All prior nulls consistent.
//  - Fix: weights NEVER touch LDS. v13's floopd (PASSED): A-only LDS dbuf
//    (0 conflicts measured), B as fragment-direct 1KB coalesced global wave
//    loads (zero redundancy: 8 n-waves own disjoint 16-col slices). LDS
//    ops/round 4608 -> ~2300.
//  - v13's real failure was write amplification (8B EA bursts) -> use v14's
//    PROVEN Hs staging + cooperative 64B/row EA stores instead.
//  - v19's PROVEN split-flag protocol (cntA/cntB) + per-iter __syncthreads
//    rhythm preserved -> weight L2 residency pattern kept (steady 1KB/iter
//    streams, 3MB/XCD demand, read once per block per round).
//  - prep kernels + gate-packed-by-4 perm np=(j>>2)*16+g*4+(j&3) + in-lane
//    shfl_xor(4/8/12) epilogue: v13-verbatim (PASSED).
// Watchdogs: FETCH >3.5e6 KB => residency broke; WRITE >500MB => store
// granularity; LDS_Block_Size must be ~33KB; scratch => VGPR overflow.
// ---------------------------------------------------------------------------

typedef __bf16 bf16x8 __attribute__((ext_vector_type(8)));
typedef float  f32x4  __attribute__((ext_vector_type(4)));

#define HSZ   (512 * 1024)  // one h buffer: 512 rows x 1024 cols (bf16)

__device__ __forceinline__ float tanh_f(float x) {
    x = fminf(30.f, fmaxf(-30.f, x));
    float e = __expf(-2.0f * x);
    return (1.0f - e) / (1.0f + e);
}

// np = (j>>2)*16 + g*4 + (j&3)  ->  original gate-major row g*1024 + j
__device__ __forceinline__ int perm_row(int np) {
    int g = (np >> 2) & 3;
    int j = ((np >> 4) << 2) | (np & 3);
    return g * 1024 + j;
}

// ---- relaxed-only flag ops (NO acquire/release -> no L2 inv/wb) ------------
__device__ __forceinline__ void spin_ge(const int* p, int target) {
    while (__hip_atomic_load(p, __ATOMIC_RELAXED, __HIP_MEMORY_SCOPE_AGENT) < target)
        __builtin_amdgcn_s_sleep(1);
}
__device__ __forceinline__ void signal_inc(int* p) {
    __hip_atomic_fetch_add(p, 1, __ATOMIC_RELAXED, __HIP_MEMORY_SCOPE_AGENT);
}
// L1-only invalidate (CU scope). Leaves L2/MALL intact; compiler fence.
__device__ __forceinline__ void inv_l1() {
    asm volatile("buffer_inv" ::: "memory");
}
// EA-point coherent dword store: bypasses L2s -> visible chip-wide.
__device__ __forceinline__ void store_ea(unsigned* p, unsigned v) {
    __hip_atomic_store(p, v, __ATOMIC_RELAXED, __HIP_MEMORY_SCOPE_AGENT);
}

// ---------------- weight prep kernels (v13-verbatim, PASSED) ----------------
// Fragment layout: for permuted col np, k: tile t = np>>4, slice ks = k>>5,
//   lane = (np&15) + ((k>>3)&3)*16, elem = lane*8 + (k&7)
// -> one wave B-frag load = 64 lanes x 16B contiguous = 1KB coalesced.

__global__ void prep_w0(const float* __restrict__ Wh0, __bf16* __restrict__ W0f) {
    int idx = blockIdx.x * 256 + threadIdx.x;       // 4096 np x 128 k-chunks
    int np = idx >> 7, c = idx & 127;
    int k = c << 3;
    int r = perm_row(np);
    const float* s = Wh0 + r * 1024 + k;
    float4 v0 = *(const float4*)s;
    float4 v1 = *(const float4*)(s + 4);
    int t = np >> 4, ks = k >> 5;
    int lane = (np & 15) + ((c & 3) << 4);
    __bf16* o = W0f + ((size_t)(t * 32 + ks) << 9) + (lane << 3);
    o[0] = (__bf16)v0.x; o[1] = (__bf16)v0.y; o[2] = (__bf16)v0.z; o[3] = (__bf16)v0.w;
    o[4] = (__bf16)v1.x; o[5] = (__bf16)v1.y; o[6] = (__bf16)v1.z; o[7] = (__bf16)v1.w;
}

__global__ void prep_w1(const float* __restrict__ Wi1, const float* __restrict__ Wh1,
                        __bf16* __restrict__ W1f) {
    int idx = blockIdx.x * 256 + threadIdx.x;       // 4096 np x 256 k-chunks
    int np = idx >> 8, c = idx & 255;
    int k = c << 3;
    int r = perm_row(np);
    const float* s = (k < 1024) ? (Wi1 + r * 1024 + k) : (Wh1 + r * 1024 + (k - 1024));
    float4 v0 = *(const float4*)s;
    float4 v1 = *(const float4*)(s + 4);
    int t = np >> 4, ks = k >> 5;                   // ks in [0,64)
    int lane = (np & 15) + ((c & 3) << 4);
    __bf16* o = W1f + ((size_t)(t * 64 + ks) << 9) + (lane << 3);
    o[0] = (__bf16)v0.x; o[1] = (__bf16)v0.y; o[2] = (__bf16)v0.z; o[3] = (__bf16)v0.w;
    o[4] = (__bf16)v1.x; o[5] = (__bf16)v1.y; o[6] = (__bf16)v1.z; o[7] = (__bf16)v1.w;
}

__global__ void prep_wfc(const float* __restrict__ Wfc, __bf16* __restrict__ Wfcf) {
    int idx = blockIdx.x * 256 + threadIdx.x;       // 768 n x 128 k-chunks
    int n = idx >> 7, c = idx & 127;
    int k = c << 3;
    int t = n >> 4, ks = k >> 5;
    int lane = (n & 15) + ((c & 3) << 4);
    __bf16* o = Wfcf + ((size_t)(t * 32 + ks) << 9) + (lane << 3);
    if (n < 672) {
        const float* s = Wfc + n * 1024 + k;
        float4 v0 = *(const float4*)s;
        float4 v1 = *(const float4*)(s + 4);
        o[0] = (__bf16)v0.x; o[1] = (__bf16)v0.y; o[2] = (__bf16)v0.z; o[3] = (__bf16)v0.w;
        o[4] = (__bf16)v1.x; o[5] = (__bf16)v1.y; o[6] = (__bf16)v1.z; o[7] = (__bf16)v1.w;
    } else {
        #pragma unroll
        for (int q = 0; q < 8; ++q) o[q] = (__bf16)0.f;
    }
}

__global__ void prep_small(const float* __restrict__ Wi0, const float* __restrict__ b0,
                           const float* __restrict__ b1,
                           float* __restrict__ Wi0p, float* __restrict__ b1p) {
    int np = blockIdx.x * 256 + threadIdx.x;
    int r = perm_row(np);
    float* o = Wi0p + np * 8;
    #pragma unroll
    for (int q = 0; q < 7; ++q) o[q] = Wi0[r * 7 + q];
    o[7] = b0[r];
    b1p[np] = b1[r];
}

// ---------------- v13 floopd (PASSED): A-LDS + fragment-direct B ------------
// 8 n-waves, wave tile 64(m) x 16(n). Per iter: 8 ds_read_b128 (A, swizzled,
// 0 conflicts), 16 MFMA, 2-4 global 1KB B-frag wave-loads (1-iter prefetch),
// 1 A global ld + 1 ds_write. A LDS [2][64][64] bf16, slot' = slot^(row&7).

template <bool D0, bool D1>
__device__ __forceinline__ void floopd(const __bf16* __restrict__ abase,
                                       const __bf16* __restrict__ b0f,
                                       const __bf16* __restrict__ b1f,
                                       int tid, __bf16* AldsB,
                                       f32x4 (&acc0)[4], f32x4 (&acc1)[4]) {
    const int a_r = tid >> 3;             // 0..63 row
    const int sl8 = tid & 7;              // 16B slot within 128B row
    const int l  = tid & 63;
    const int lj = l & 15, lq = l >> 4;
    const int r7 = lj & 7;

    const __bf16* arw = abase + a_r * 1024 + sl8 * 8;
    const int woff = a_r * 64 + ((sl8 ^ (a_r & 7)) << 3);   // swizzled write

    bf16x8 P0[2], P1[2], Q0[2], Q1[2];
    uint4 rA0, rA1;

    auto ldB = [&](int it, bf16x8 (&r0)[2], bf16x8 (&r1)[2]) {
        #pragma unroll
        for (int s = 0; s < 2; ++s) {
            const int ks = 2 * it + s;
            if (D0) r0[s] = *(const bf16x8*)(b0f + ((size_t)ks << 9));
            if (D1) r1[s] = *(const bf16x8*)(b1f + ((size_t)ks << 9));
        }
    };
    auto mm = [&](int bo, bf16x8 (&r0)[2], bf16x8 (&r1)[2]) {
        const __bf16* Ab = AldsB + bo * 4096;
        #pragma unroll
        for (int s = 0; s < 2; ++s) {
            #pragma unroll
            for (int mi = 0; mi < 4; ++mi) {
                bf16x8 af = *(const bf16x8*)(Ab + (mi * 16 + lj) * 64 +
                                             ((((s << 2) | lq) ^ r7) << 3));
                if (D0) acc0[mi] = __builtin_amdgcn_mfma_f32_16x16x32_bf16(af, r0[s], acc0[mi], 0, 0, 0);
                if (D1) acc1[mi] = __builtin_amdgcn_mfma_f32_16x16x32_bf16(af, r1[s], acc1[mi], 0, 0, 0);
            }
        }
    };

    // prologue: A(0) -> buf0, A(1) -> rA1, B(0) -> P
    {
        uint4 t0 = *(const uint4*)(arw);
        *(uint4*)(AldsB + woff) = t0;
    }
    rA1 = *(const uint4*)(arw + 64);
    ldB(0, P0, P1);
    __syncthreads();

    for (int i2 = 0; i2 < 8; ++i2) {
        const int it = i2 * 2;
        // even sub-iter: consume buf0 + P(it); prefetch issued FIRST
        ldB(it + 1, Q0, Q1);
        if (it + 2 < 16) rA0 = *(const uint4*)(arw + (it + 2) * 64);
        mm(0, P0, P1);
        *(uint4*)(AldsB + 4096 + woff) = rA1;            // A(it+1) -> buf1
        __syncthreads();
        // odd sub-iter: consume buf1 + Q(it+1)
        if (it + 2 < 16) ldB(it + 2, P0, P1);
        if (it + 3 < 16) rA1 = *(const uint4*)(arw + (it + 3) * 64);
        mm(1, Q0, Q1);
        if (it + 2 < 16) *(uint4*)(AldsB + woff) = rA0;  // A(it+2) -> buf0
        __syncthreads();
    }
}

// ---------------- persistent fused LSTM kernel ------------------------------
// 256 blocks, 1/CU, 512 threads. xcd owns gate-col slice [512x,512x+512);
// slot -> mt (0..7) x nb (0..3). Round r: phase A = L0(r) [r<128] + Wi1-half
// of L1(r-1) on h_a; phase B = Wh1-half on h_b + L1 epilogue.
// cntA[mt] target 32r gates h_a(r-1); cntB[mt] target 32r gates h_b(r-2).

__global__ __launch_bounds__(512)
void lstm_persist(const float* __restrict__ x,
                  const __bf16* __restrict__ W0p, const __bf16* __restrict__ W1p,
                  const __bf16* __restrict__ Wfcp,
                  const float* __restrict__ Wi0p, const float* __restrict__ b1p,
                  const float* __restrict__ bfc,
                  __bf16* __restrict__ bufA, __bf16* __restrict__ bufB,
                  char* __restrict__ flagpage, float* __restrict__ out) {
    __shared__ __attribute__((aligned(16))) __bf16 Alds[2 * 64 * 64];  // 16 KB
    __shared__ unsigned Hs[2][1024];                                   //  8 KB
    __shared__ float Aux1[128];
    __shared__ float Xlds[64 * 9];
    __shared__ float Wxlds[128 * 9];
    __shared__ int role[2];

    const int tid = threadIdx.x;

    // ---- claim XCD-local role ----
    if (tid == 0) {
        int xcd = __builtin_amdgcn_s_getreg(63508) & 7;   // HW_REG_XCC_ID
        int* xcnt = (int*)(flagpage + 1024) + xcd;
        int slot = __hip_atomic_fetch_add(xcnt, 1, __ATOMIC_RELAXED,
                                          __HIP_MEMORY_SCOPE_AGENT);
        role[0] = xcd; role[1] = slot;
    }
    __syncthreads();
    const int xcd = role[0];
    const int sl  = role[1];          // 0..31
    const int mt = sl >> 2, nb = sl & 3;
    const int m0 = mt * 64;
    const int n0 = xcd * 512 + nb * 128;
    int* cntA = (int*)(flagpage + (size_t)mt * 64);          // offsets 0..448
    int* cntB = (int*)(flagpage + 512 + (size_t)mt * 64);    // offsets 512..960

    // one-time epilogue constants
    if (tid < 128) {
        Aux1[tid] = b1p[n0 + tid];
    } else if (tid < 256) {
        int nl = tid - 128;
        const float* sp = Wi0p + (n0 + nl) * 8;
        float* d = Wxlds + nl * 9;
        #pragma unroll
        for (int q = 0; q < 8; ++q) d[q] = sp[q];
    }

    const int l  = tid & 63, w = tid >> 6;   // wave w = n-slice owner
    const int lj = l & 15,  lq = l >> 4;

    // per-wave fragment base pointers (tile base + lane elem offset)
    const int t = (n0 >> 4) + w;
    const __bf16* b0f = W0p + ((size_t)t << 14) + (l << 3);  // 32 slices/tile
    const __bf16* b1f = W1p + ((size_t)t << 15) + (l << 3);  // 64 slices/tile

    // lane gate id: np&15 = g*4 + u
    const float g2 = (((l >> 2) & 3) == 2) ? 1.f : 0.f;
    const float sc = 1.f + g2;
    const float* wx = Wxlds + (w * 16 + lj) * 9;

    float c0[16], c1[16];
    #pragma unroll
    for (int q = 0; q < 16; ++q) { c0[q] = 0.f; c1[q] = 0.f; }

    f32x4 acc0[4], acc1[4];

    for (int r = 0; r <= 128; ++r) {
        const bool do0 = (r < 128), do1 = (r > 0);
        const __bf16* haPrev = bufA + (size_t)(r % 3) * HSZ;        // h_a(r-1)
        __bf16*       haOut  = bufA + (size_t)((r + 1) % 3) * HSZ;  // h_a(r)
        const __bf16* hbPrev = bufB + (size_t)((r + 2) % 3) * HSZ;  // h_b(r-2)
        __bf16*       hbOut  = bufB + (size_t)(r % 3) * HSZ;        // h_b(r-1)

        // ================= phase A: needs h_a(r-1) =========================
        if (tid == 0) spin_ge(cntA, 32 * r);
        __syncthreads();
        inv_l1();

        // stage x_r (read-only input)
        if (do0 && tid < 64) {
            const float* xr = x + (m0 + tid) * 896 + r * 7;
            float* d = Xlds + tid * 9;
            #pragma unroll
            for (int q = 0; q < 7; ++q) d[q] = xr[q];
            d[7] = 1.0f;
        }

        #pragma unroll
        for (int j = 0; j < 4; ++j) {
            acc0[j] = (f32x4){0.f, 0.f, 0.f, 0.f};
            acc1[j] = (f32x4){0.f, 0.f, 0.f, 0.f};
        }

        const __bf16* abase = haPrev + m0 * 1024;
        if (do0 && do1)
            floopd<true, true >(abase, b0f, b1f, tid, Alds, acc0, acc1);
        else if (do0)
            floopd<true, false>(abase, b0f, b1f, tid, Alds, acc0, acc1);
        else   // r == 128: Wi1-half on h_a(127)
            floopd<false, true>(abase, b0f, b1f, tid, Alds, acc0, acc1);

        if (do0) {   // L0 epilogue: gates in-lane -> shfl combine -> stage Hs
            #pragma unroll
            for (int mi = 0; mi < 4; ++mi) {
                #pragma unroll
                for (int rr = 0; rr < 4; ++rr) {
                    int row = mi * 16 + lq * 4 + rr;
                    float pre = acc0[mi][rr];
                    const float* xr = Xlds + row * 9;
                    #pragma unroll
                    for (int q = 0; q < 8; ++q) pre += xr[q] * wx[q];
                    float px = fminf(30.f, fmaxf(-30.f, pre * sc));
                    float e = __expf(-px);
                    float a = (1.f - g2 * e) / (1.f + e);   // sigm / tanh
                    float t4  = __shfl_xor(a, 4, 64);       // f
                    float t8  = __shfl_xor(a, 8, 64);       // g
                    float t12 = __shfl_xor(a, 12, 64);      // o
                    float cn = t4 * c0[mi * 4 + rr] + a * t8;
                    c0[mi * 4 + rr] = cn;
                    float hv = t12 * tanh_f(cn);
                    unsigned u32 = __builtin_bit_cast(unsigned, hv);
                    unsigned hu = (u32 + 0x7fffu + ((u32 >> 16) & 1u)) >> 16;
                    int pv = __shfl_xor((int)hu, 1, 64);
                    if ((lj < 4) && ((l & 1) == 0))
                        Hs[0][row * 16 + w * 2 + (lj >> 1)] = hu | ((unsigned)pv << 16);
                }
            }
        }
        __syncthreads();                 // Hs[0] staged by all waves

        if (do0) {   // cooperative wide EA stores: 4 rows x 64B per wave instr
            const int dwbase = n0 >> 3;
            #pragma unroll
            for (int pass = 0; pass < 2; ++pass) {
                int d = pass * 512 + tid;
                int row = d >> 4, col = d & 15;
                size_t off = (size_t)(m0 + row) * 512 + dwbase + col;
                store_ea((unsigned*)haOut + off, Hs[0][d]);
            }
        }
        __syncthreads();                 // vmcnt(0): h_a stores performed
        if (tid == 0) signal_inc(cntA);

        // ================= phase B: needs h_b(r-2) =========================
        if (tid == 0) spin_ge(cntB, 32 * r);
        __syncthreads();
        inv_l1();

        if (do1) {   // h_b(r-2) half of layer-1 GEMM (k in [1024,2048))
            floopd<false, true>(hbPrev + m0 * 1024, b0f, b1f + (32 << 9),
                                tid, Alds, acc0, acc1);

            // L1 epilogue -> stage Hs[1]
            const float b1v = Aux1[w * 16 + lj];
            #pragma unroll
            for (int mi = 0; mi < 4; ++mi) {
                #pragma unroll
                for (int rr = 0; rr < 4; ++rr) {
                    int row = mi * 16 + lq * 4 + rr;
                    float pre = acc1[mi][rr] + b1v;
                    float px = fminf(30.f, fmaxf(-30.f, pre * sc));
                    float e = __expf(-px);
                    float a = (1.f - g2 * e) / (1.f + e);
                    float t4  = __shfl_xor(a, 4, 64);
                    float t8  = __shfl_xor(a, 8, 64);
                    float t12 = __shfl_xor(a, 12, 64);
                    float cn = t4 * c1[mi * 4 + rr] + a * t8;
                    c1[mi * 4 + rr] = cn;
                    float hv = t12 * tanh_f(cn);
                    unsigned u32 = __builtin_bit_cast(unsigned, hv);
                    unsigned hu = (u32 + 0x7fffu + ((u32 >> 16) & 1u)) >> 16;
                    int pv = __shfl_xor((int)hu, 1, 64);
                    if ((lj < 4) && ((l & 1) == 0))
                        Hs[1][row * 16 + w * 2 + (lj >> 1)] = hu | ((unsigned)pv << 16);
                }
            }
        }
        __syncthreads();                 // Hs[1] staged

        if (do1) {
            const int dwbase = n0 >> 3;
            #pragma unroll
            for (int pass = 0; pass < 2; ++pass) {
                int d = pass * 512 + tid;
                int row = d >> 4, col = d & 15;
                size_t off = (size_t)(m0 + row) * 512 + dwbase + col;
                store_ea((unsigned*)hbOut + off, Hs[1][d]);
            }
        }
        __syncthreads();                 // vmcnt(0): h_b stores performed
        if (tid == 0) signal_inc(cntB);
    }

    // ---- final FC: pred = h_b(127) @ Wfc^T + bfc  (nb==0, xcd<6) -----------
    if (nb == 0 && xcd < 6) {
        const int n0fc = xcd * 128;
        if (tid == 0) spin_ge(cntB, 32 * 129);
        __syncthreads();
        inv_l1();
        if (tid < 128) {
            int n = n0fc + tid;
            Aux1[tid] = (n < 672) ? bfc[n] : 0.f;
        }
        __syncthreads();
        #pragma unroll
        for (int j = 0; j < 4; ++j)
            acc0[j] = (f32x4){0.f, 0.f, 0.f, 0.f};
        const __bf16* bfcf = Wfcp + ((size_t)(xcd * 8 + w) << 14) + (l << 3);
        // h_b(127) written in round 128 into bufB slot 128%3 = 2
        floopd<true, false>(bufB + (size_t)2 * HSZ + m0 * 1024,
                            bfcf, nullptr, tid, Alds, acc0, acc1);
        const int n = n0fc + w * 16 + lj;
        if (n < 672) {
            const float bv = Aux1[w * 16 + lj];
            #pragma unroll
            for (int mi = 0; mi < 4; ++mi) {
                #pragma unroll
                for (int rr = 0; rr < 4; ++rr) {
                    int m = m0 + mi * 16 + lq * 4 + rr;
                    out[m * 672 + n] = acc0[mi][rr] + bv;
                }
            }
        }
    }
}

// ---------------- workspace layout (bytes) ----------------------------------
#define O_W0P   0u            // 4096*1024*2  = 8388608
#define O_W1P   8388608u      // 4096*2048*2  = 16777216
#define O_WFCP  25165824u     // 768*1024*2   = 1572864
#define O_WI0P  26738688u     // 4096*8*4     = 131072
#define O_B1P   26869760u     // 4096*4       = 16384
#define O_FLG   26886144u     // 2048: cntA@mt*64, cntB@512+mt*64, xcnt@1024
#define O_BA    26888192u     // bufA[3] = 3*1048576  (slot0 zeroed = h_a(-1))
#define O_BB    30033920u     // bufB[3] = 3*1048576  (slot0 zeroed = h_b(-1))
#define WS_NEED 33179648u

extern "C" void kernel_launch(void* const* d_in, const int* in_sizes, int n_in,
                              void* d_out, int out_size, void* d_ws, size_t ws_size,
                              hipStream_t stream) {
    const float* x   = (const float*)d_in[0];
    const float* Wi0 = (const float*)d_in[1];
    const float* Wh0 = (const float*)d_in[2];
    const float* b0  = (const float*)d_in[3];
    const float* Wi1 = (const float*)d_in[4];
    const float* Wh1 = (const float*)d_in[5];
    const float* b1  = (const float*)d_in[6];
    const float* Wfc = (const float*)d_in[7];
    const float* bfc = (const float*)d_in[8];
    float* out = (float*)d_out;
    char*  ws  = (char*)d_ws;
    if (ws_size < WS_NEED) return;

    __bf16* W0p  = (__bf16*)(ws + O_W0P);
    __bf16* W1p  = (__bf16*)(ws + O_W1P);
    __bf16* Wfcp = (__bf16*)(ws + O_WFCP);
    float*  Wi0p = (float*)(ws + O_WI0P);
    float*  b1p  = (float*)(ws + O_B1P);
    char*   flg  = (char*)(ws + O_FLG);
    __bf16* bufA = (__bf16*)(ws + O_BA);
    __bf16* bufB = (__bf16*)(ws + O_BB);

    // zero flags + bufA slot0 (contiguous), and bufB slot0
    hipMemsetAsync(ws + O_FLG, 0, 2048u + 1048576u, stream);
    hipMemsetAsync(ws + O_BB, 0, 1048576u, stream);

    prep_w0   <<<2048, 256, 0, stream>>>(Wh0, W0p);
    prep_w1   <<<4096, 256, 0, stream>>>(Wi1, Wh1, W1p);
    prep_wfc  <<<384,  256, 0, stream>>>(Wfc, Wfcp);
    prep_small<<<16,   256, 0, stream>>>(Wi0, b0, b1, Wi0p, b1p);

    lstm_persist<<<256, 512, 0, stream>>>(x, W0p, W1p, Wfcp, Wi0p, b1p, bfc,
                                          bufA, bufB, flg, out);
}

// Round 13
// 2855.262 us; speedup vs baseline: 1.9351x; 1.9351x over previous
//
#include <hip/hip_runtime.h>
#include <hip/hip_bf16.h>

// ---------------------------------------------------------------------------
// LSTM_66675072303478: 2-layer LSTM (B=512,S=128,E=7,H=1024) + FC(1024->672)
//
// v24 = v19 (2828us, best verified) + one micro-fix: x_r staging issued at
// the TOP of each round, BEFORE the flag spin (x is a read-only input with
// no flag dependency) -> its HBM/MALL latency hides under the wait instead
// of serializing after inv_l1.
//
// Session ledger (v11..v23): any deviation from this kernel's global access
// pattern breaks weight L2/MALL residency (v12/v13/v14/v23: FETCH 2.5-9x,
// dur tracks hbm_bytes/BW); every pattern-preserving structural change is
// neutral (v16 vmcnt, v17 -28% LDS, v20 2x occupancy, v21 dual-chain ILP);
// v22 A-burst spilled (WRITE 8.7GB watchdog). Only sync-protocol work won
// (v19 split flags +3%). This basin's floor is ~2830us; v24 consolidates.
//  - proven & kept: 4(m)x2(n) waves, wave tile 16x64, XOR swizzle
//    phys=row*128+((chunk^(row&7))<<4) (0 conflicts), gate-interleaved
//    epilogue, EA h stores + 3-slot rotation + L1-only inv, split flags
//    cntA/cntB (phase A publishes h_a ~60% into round), weights L2-resident.
// ---------------------------------------------------------------------------

typedef __bf16 bf16x8 __attribute__((ext_vector_type(8)));
typedef float  f32x4  __attribute__((ext_vector_type(4)));

#define HSZ   (512 * 1024)  // one h buffer: 512 rows x 1024 cols (bf16)

__device__ __forceinline__ float sigm_f(float x) {
    x = fminf(30.f, fmaxf(-30.f, x));
    return 1.0f / (1.0f + __expf(-x));
}
__device__ __forceinline__ float tanh_f(float x) {
    x = fminf(30.f, fmaxf(-30.f, x));
    float e = __expf(-2.0f * x);
    return (1.0f - e) / (1.0f + e);
}

// n' = (j/16)*64 + g*16 + (j%16)  ->  original gate-major row g*1024 + j
__device__ __forceinline__ int perm_row(int np) {
    int g = (np >> 4) & 3;
    int j = ((np >> 6) << 4) | (np & 15);
    return g * 1024 + j;
}

// ---- relaxed-only flag ops (NO acquire/release -> no L2 inv/wb) ------------
__device__ __forceinline__ void spin_ge(const int* p, int target) {
    while (__hip_atomic_load(p, __ATOMIC_RELAXED, __HIP_MEMORY_SCOPE_AGENT) < target)
        __builtin_amdgcn_s_sleep(1);
}
__device__ __forceinline__ void signal_inc(int* p) {
    __hip_atomic_fetch_add(p, 1, __ATOMIC_RELAXED, __HIP_MEMORY_SCOPE_AGENT);
}
// L1-only invalidate (CU scope). Leaves L2/MALL intact; compiler fence.
__device__ __forceinline__ void inv_l1() {
    asm volatile("buffer_inv" ::: "memory");
}
// EA-point coherent dword store: bypasses L2s -> visible chip-wide.
__device__ __forceinline__ void store_ea(unsigned* p, unsigned v) {
    __hip_atomic_store(p, v, __ATOMIC_RELAXED, __HIP_MEMORY_SCOPE_AGENT);
}

// ---------------- weight prep kernels (run every call) ----------------------

__global__ void prep_w0(const float* __restrict__ Wh0, __bf16* __restrict__ W0p) {
    int idx = blockIdx.x * 256 + threadIdx.x;
    int np = idx >> 8, k4 = (idx & 255) << 2;
    int r = perm_row(np);
    float4 v = *(const float4*)(Wh0 + r * 1024 + k4);
    __bf16* o = W0p + np * 1024 + k4;
    o[0] = (__bf16)v.x; o[1] = (__bf16)v.y; o[2] = (__bf16)v.z; o[3] = (__bf16)v.w;
}

__global__ void prep_w1(const float* __restrict__ Wi1, const float* __restrict__ Wh1,
                        __bf16* __restrict__ W1p) {
    int idx = blockIdx.x * 256 + threadIdx.x;
    int np = idx >> 9, k4 = (idx & 511) << 2;
    int r = perm_row(np);
    const float* s = (k4 < 1024) ? (Wi1 + r * 1024 + k4) : (Wh1 + r * 1024 + (k4 - 1024));
    float4 v = *(const float4*)s;
    __bf16* o = W1p + np * 2048 + k4;
    o[0] = (__bf16)v.x; o[1] = (__bf16)v.y; o[2] = (__bf16)v.z; o[3] = (__bf16)v.w;
}

__global__ void prep_wfc(const float* __restrict__ Wfc, __bf16* __restrict__ Wfcp) {
    int idx = blockIdx.x * 256 + threadIdx.x;
    int n = idx >> 8, k4 = (idx & 255) << 2;
    __bf16* o = Wfcp + n * 1024 + k4;
    if (n < 672) {
        float4 v = *(const float4*)(Wfc + n * 1024 + k4);
        o[0] = (__bf16)v.x; o[1] = (__bf16)v.y; o[2] = (__bf16)v.z; o[3] = (__bf16)v.w;
    } else {
        o[0] = (__bf16)0.f; o[1] = (__bf16)0.f; o[2] = (__bf16)0.f; o[3] = (__bf16)0.f;
    }
}

__global__ void prep_small(const float* __restrict__ Wi0, const float* __restrict__ b0,
                           const float* __restrict__ b1,
                           float* __restrict__ Wi0p, float* __restrict__ b1p) {
    int np = blockIdx.x * 256 + threadIdx.x;
    int r = perm_row(np);
    float* o = Wi0p + np * 8;
    #pragma unroll
    for (int q = 0; q < 7; ++q) o[q] = Wi0[r * 7 + q];
    o[7] = b0[r];
    b1p[np] = b1[r];
}

// ---------------- fused pipelined K=1024 sub-loop (512 threads) -------------
// Tile 64x128, 8 waves in 4(m)x2(n), wave tile 16x64, BK=64, LDS dbuf,
// 1 barrier/iter, global loads 2 iters ahead. D0 -> acc0 (W0), D1 -> acc1.
// LDS layout (A 64x64, B0/B1 128x64 per buf): 128B rows, 16B chunks stored at
//   phys = row*128 + ((chunk ^ (row&7))<<4)   -> conflict-free rd AND wr.

template <bool D0, bool D1>
__device__ __forceinline__ void floop(const __bf16* __restrict__ abase,
                                      const __bf16* __restrict__ w0row,
                                      const __bf16* __restrict__ w1row,
                                      int tid,
                                      char* AldsB, char* B0ldsB, char* B1ldsB,
                                      f32x4 (&acc0)[4], f32x4 (&acc1)[4]) {
    const int a_r = tid >> 3;             // 0..63
    const int a_c = (tid & 7) << 3;       // 0..56 step 8 (16 B)
    const int b_r = tid >> 2;             // 0..127
    const int b_c = (tid & 3) << 4;       // 0,16,32,48 (2 x 16 B each)
    const int l  = tid & 63, w = tid >> 6;
    const int wm = w & 3,   wn = w >> 2;
    const int lj = l & 15,  lq = l >> 4;
    const int r7 = lj & 7;

    const __bf16* arw = abase + a_r * 1024 + a_c;

    // swizzled LDS byte offsets (writes)
    const int awr  = a_r * 128 + (((tid & 7) ^ (a_r & 7)) << 4);
    const int bwr0 = b_r * 128 + (((((tid & 3) << 1) | 0) ^ (b_r & 7)) << 4);
    const int bwr1 = b_r * 128 + (((((tid & 3) << 1) | 1) ^ (b_r & 7)) << 4);
    // swizzled chunk offsets (reads), chunk = (s<<2)|lq
    const int rc0 = ((lq     ) ^ r7) << 4;   // s = 0
    const int rc1 = ((lq | 4 ) ^ r7) << 4;   // s = 1

    uint4 ra, rb00, rb01, rb10, rb11;
    auto ld = [&](int k0) {
        ra = *(const uint4*)(arw + k0);
        if (D0) {
            const __bf16* p = w0row + k0;
            rb00 = *(const uint4*)(p);
            rb01 = *(const uint4*)(p + 8);
        }
        if (D1) {
            const __bf16* p = w1row + k0;
            rb10 = *(const uint4*)(p);
            rb11 = *(const uint4*)(p + 8);
        }
    };
    auto wr = [&](int buf) {
        *(uint4*)(AldsB + buf * 8192 + awr) = ra;
        if (D0) {
            char* Bl = B0ldsB + buf * 16384;
            *(uint4*)(Bl + bwr0) = rb00;
            *(uint4*)(Bl + bwr1) = rb01;
        }
        if (D1) {
            char* Bl = B1ldsB + buf * 16384;
            *(uint4*)(Bl + bwr0) = rb10;
            *(uint4*)(Bl + bwr1) = rb11;
        }
    };

    ld(0);
    wr(0);
    ld(64);
    __syncthreads();

    const char* Ap  = AldsB  + (wm * 16 + lj) * 128;
    const char* B0p = B0ldsB + (wn * 64 + lj) * 128;
    const char* B1p = B1ldsB + (wn * 64 + lj) * 128;

    for (int it = 0; it < 16; ++it) {
        const int bo = it & 1;
        const char* Ab  = Ap  + bo * 8192;
        const char* B0b = B0p + bo * 16384;
        const char* B1b = B1p + bo * 16384;
        #pragma unroll
        for (int s = 0; s < 2; ++s) {
            const int rc = s ? rc1 : rc0;
            bf16x8 af = *(const bf16x8*)(Ab + rc);
            #pragma unroll
            for (int ni = 0; ni < 4; ++ni) {
                if (D0) {
                    bf16x8 b0 = *(const bf16x8*)(B0b + ni * 2048 + rc);
                    acc0[ni] = __builtin_amdgcn_mfma_f32_16x16x32_bf16(af, b0, acc0[ni], 0, 0, 0);
                }
                if (D1) {
                    bf16x8 b1 = *(const bf16x8*)(B1b + ni * 2048 + rc);
                    acc1[ni] = __builtin_amdgcn_mfma_f32_16x16x32_bf16(af, b1, acc1[ni], 0, 0, 0);
                }
            }
        }
        if (it + 1 < 16) wr((it + 1) & 1);       // data loaded 1 iter ago
        if (it + 2 < 16) ld((it + 2) * 64);      // 2-iter prefetch distance
        __syncthreads();
    }
}

// ---------------- persistent fused LSTM kernel ------------------------------
// 256 blocks, 1/CU, 512 threads. xcd owns gate-col slice [512x,512x+512);
// slot -> mt (0..7) x nb (0..3). Round r: phase A = L0(r) [r<128] + Wi1-half
// of L1(r-1); phase B = Wh1-half + L1 epilogue. cntA[mt] target 32r gates
// h_a(r-1); cntB[mt] target 32r gates h_b(r-2).

__global__ __launch_bounds__(512)
void lstm_persist(const float* __restrict__ x,
                  const __bf16* __restrict__ W0p, const __bf16* __restrict__ W1p,
                  const __bf16* __restrict__ Wfcp,
                  const float* __restrict__ Wi0p, const float* __restrict__ b1p,
                  const float* __restrict__ bfc,
                  __bf16* __restrict__ bufA, __bf16* __restrict__ bufB,
                  char* __restrict__ flagpage, float* __restrict__ out) {
    __shared__ __attribute__((aligned(16))) char Alds[2 * 8192];      // 16 KB
    __shared__ __attribute__((aligned(16))) char B0lds[2 * 16384];    // 32 KB
    __shared__ __attribute__((aligned(16))) char B1lds[2 * 16384];    // 32 KB
    __shared__ float Aux1[128];
    __shared__ float Xlds[64 * 9];
    __shared__ float Wxlds[128 * 9];
    __shared__ int role[2];

    const int tid = threadIdx.x;

    // ---- claim XCD-local role ----
    if (tid == 0) {
        int xcd = __builtin_amdgcn_s_getreg(63508) & 7;   // HW_REG_XCC_ID
        int* xcnt = (int*)(flagpage + 1024) + xcd;
        int slot = __hip_atomic_fetch_add(xcnt, 1, __ATOMIC_RELAXED,
                                          __HIP_MEMORY_SCOPE_AGENT);
        role[0] = xcd; role[1] = slot;
    }
    __syncthreads();
    const int xcd = role[0];
    const int sl  = role[1];          // 0..31
    const int mt = sl >> 2, nb = sl & 3;
    const int m0 = mt * 64;
    const int n0 = xcd * 512 + nb * 128;
    int* cntA = (int*)(flagpage + (size_t)mt * 64);          // offsets 0..448
    int* cntB = (int*)(flagpage + 512 + (size_t)mt * 64);    // offsets 512..960

    // one-time epilogue constants
    if (tid < 128) {
        Aux1[tid] = b1p[n0 + tid];
    } else if (tid < 256) {
        int nl = tid - 128;
        const float* sp = Wi0p + (n0 + nl) * 8;
        float* d = Wxlds + nl * 9;
        #pragma unroll
        for (int q = 0; q < 8; ++q) d[q] = sp[q];
    }

    const int b_r = tid >> 2;
    const int b_c = (tid & 3) << 4;
    const int l  = tid & 63, w = tid >> 6;
    const int wm = w & 3,   wn = w >> 2;
    const int lj = l & 15,  lq = l >> 4;
    const int jc = (n0 >> 2) + wn * 16 + lj;   // h column in [0,1024)

    const __bf16* w0row = W0p + (size_t)(n0 + b_r) * 1024 + b_c;
    const __bf16* w1row = W1p + (size_t)(n0 + b_r) * 2048 + b_c;

    float c0[4], c1[4];
    #pragma unroll
    for (int r = 0; r < 4; ++r) { c0[r] = 0.f; c1[r] = 0.f; }

    f32x4 acc0[4], acc1[4];

    for (int r = 0; r <= 128; ++r) {
        const bool do0 = (r < 128), do1 = (r > 0);
        const __bf16* haPrev = bufA + (size_t)(r % 3) * HSZ;        // h_a(r-1)
        __bf16*       haOut  = bufA + (size_t)((r + 1) % 3) * HSZ;  // h_a(r)
        const __bf16* hbPrev = bufB + (size_t)((r + 2) % 3) * HSZ;  // h_b(r-2)
        __bf16*       hbOut  = bufB + (size_t)(r % 3) * HSZ;        // h_b(r-1)

        // stage x_r BEFORE the flag wait: x is a read-only input with no
        // flag dependency; all threads passed round r-1's final barrier, so
        // no reader of the old Xlds remains. Latency hides under the spin.
        if (do0 && tid < 64) {
            const float* xr = x + (m0 + tid) * 896 + r * 7;
            float* d = Xlds + tid * 9;
            #pragma unroll
            for (int q = 0; q < 7; ++q) d[q] = xr[q];
            d[7] = 1.0f;
        }

        // ================= phase A: needs h_a(r-1) =========================
        if (tid == 0) spin_ge(cntA, 32 * r);
        __syncthreads();
        inv_l1();

        #pragma unroll
        for (int j = 0; j < 4; ++j) {
            acc0[j] = (f32x4){0.f, 0.f, 0.f, 0.f};
            acc1[j] = (f32x4){0.f, 0.f, 0.f, 0.f};
        }

        const __bf16* abase = haPrev + m0 * 1024;
        if (do0 && do1)
            floop<true, true >(abase, w0row, w1row, tid, Alds, B0lds, B1lds, acc0, acc1);
        else if (do0)
            floop<true, false>(abase, w0row, w1row, tid, Alds, B0lds, B1lds, acc0, acc1);
        else
            floop<false, true>(abase, w0row, w1row, tid, Alds, B0lds, B1lds, acc0, acc1);

        if (do0) {   // L0 epilogue: cell update + EA store h_a(r)
            #pragma unroll
            for (int rr = 0; rr < 4; ++rr) {
                int ml = wm * 16 + lq * 4 + rr;
                int m  = m0 + ml;
                float pre[4];
                #pragma unroll
                for (int g = 0; g < 4; ++g) pre[g] = acc0[g][rr];
                const float* xr = Xlds + ml * 9;
                #pragma unroll
                for (int g = 0; g < 4; ++g) {
                    const float* wx = Wxlds + (wn * 64 + g * 16 + lj) * 9;
                    float sv = 0.f;
                    #pragma unroll
                    for (int q = 0; q < 8; ++q) sv += xr[q] * wx[q];
                    pre[g] += sv;
                }
                float ig = sigm_f(pre[0]);
                float fg = sigm_f(pre[1]);
                float gv = tanh_f(pre[2]);
                float og = sigm_f(pre[3]);
                float cn = fg * c0[rr] + ig * gv;
                c0[rr] = cn;
                float hv = og * tanh_f(cn);
                unsigned u32 = __builtin_bit_cast(unsigned, hv);
                unsigned hu = (u32 + 0x7fffu + ((u32 >> 16) & 1u)) >> 16;
                int pv = __shfl_xor((int)hu, 1, 64);
                if ((lj & 1) == 0)
                    store_ea((unsigned*)(haOut + (size_t)m * 1024 + jc),
                             hu | ((unsigned)pv << 16));
            }
        }
        __syncthreads();                 // vmcnt(0): h_a stores performed
        if (tid == 0) signal_inc(cntA);

        // ================= phase B: needs h_b(r-2) =========================
        if (tid == 0) spin_ge(cntB, 32 * r);
        __syncthreads();
        inv_l1();

        if (do1) {   // h_b(r-2) half of layer-1 GEMM (k in [1024,2048))
            floop<false, true>(hbPrev + m0 * 1024, w0row, w1row + 1024,
                               tid, Alds, B0lds, B1lds, acc0, acc1);

            // L1 epilogue: cell update + EA store h_b(r-1)
            #pragma unroll
            for (int rr = 0; rr < 4; ++rr) {
                int m = m0 + wm * 16 + lq * 4 + rr;
                float pre[4];
                #pragma unroll
                for (int g = 0; g < 4; ++g)
                    pre[g] = acc1[g][rr] + Aux1[wn * 64 + g * 16 + lj];
                float ig = sigm_f(pre[0]);
                float fg = sigm_f(pre[1]);
                float gv = tanh_f(pre[2]);
                float og = sigm_f(pre[3]);
                float cn = fg * c1[rr] + ig * gv;
                c1[rr] = cn;
                float hv = og * tanh_f(cn);
                unsigned u32 = __builtin_bit_cast(unsigned, hv);
                unsigned hu = (u32 + 0x7fffu + ((u32 >> 16) & 1u)) >> 16;
                int pv = __shfl_xor((int)hu, 1, 64);
                if ((lj & 1) == 0)
                    store_ea((unsigned*)(hbOut + (size_t)m * 1024 + jc),
                             hu | ((unsigned)pv << 16));
            }
        }
        __syncthreads();                 // vmcnt(0): h_b stores performed
        if (tid == 0) signal_inc(cntB);
    }

    // ---- final FC: pred = h_b(127) @ Wfc^T + bfc  (nb==0, xcd<6) -----------
    if (nb == 0 && xcd < 6) {
        const int n0fc = xcd * 128;
        if (tid == 0) spin_ge(cntB, 32 * 129);
        __syncthreads();
        inv_l1();
        if (tid < 128) {
            int n = n0fc + tid;
            Aux1[tid] = (n < 672) ? bfc[n] : 0.f;
        }
        #pragma unroll
        for (int j = 0; j < 4; ++j)
            acc0[j] = (f32x4){0.f, 0.f, 0.f, 0.f};
        // h_b(127) written in round 128 into bufB slot 128%3 = 2
        floop<true, false>(bufB + (size_t)2 * HSZ + m0 * 1024,
                           Wfcp + (size_t)(n0fc + b_r) * 1024 + b_c, nullptr,
                           tid, Alds, B0lds, B1lds, acc0, acc1);
        #pragma unroll
        for (int rr = 0; rr < 4; ++rr) {
            int m = m0 + wm * 16 + lq * 4 + rr;
            #pragma unroll
            for (int ni = 0; ni < 4; ++ni) {
                int n = n0fc + wn * 64 + ni * 16 + lj;
                if (n < 672)
                    out[m * 672 + n] = acc0[ni][rr] + Aux1[wn * 64 + ni * 16 + lj];
            }
        }
    }
}

// ---------------- workspace layout (bytes) ----------------------------------
#define O_W0P   0u            // 4096*1024*2  = 8388608
#define O_W1P   8388608u      // 4096*2048*2  = 16777216
#define O_WFCP  25165824u     // 768*1024*2   = 1572864
#define O_WI0P  26738688u     // 4096*8*4     = 131072
#define O_B1P   26869760u     // 4096*4       = 16384
#define O_FLG   26886144u     // 2048: cntA@mt*64, cntB@512+mt*64, xcnt@1024
#define O_BA    26888192u     // bufA[3] = 3*1048576  (slot0 zeroed = h_a(-1))
#define O_BB    30033920u     // bufB[3] = 3*1048576  (slot0 zeroed = h_b(-1))
#define WS_NEED 33179648u

extern "C" void kernel_launch(void* const* d_in, const int* in_sizes, int n_in,
                              void* d_out, int out_size, void* d_ws, size_t ws_size,
                              hipStream_t stream) {
    const float* x   = (const float*)d_in[0];
    const float* Wi0 = (const float*)d_in[1];
    const float* Wh0 = (const float*)d_in[2];
    const float* b0  = (const float*)d_in[3];
    const float* Wi1 = (const float*)d_in[4];
    const float* Wh1 = (const float*)d_in[5];
    const float* b1  = (const float*)d_in[6];
    const float* Wfc = (const float*)d_in[7];
    const float* bfc = (const float*)d_in[8];
    float* out = (float*)d_out;
    char*  ws  = (char*)d_ws;
    if (ws_size < WS_NEED) return;

    __bf16* W0p  = (__bf16*)(ws + O_W0P);
    __bf16* W1p  = (__bf16*)(ws + O_W1P);
    __bf16* Wfcp = (__bf16*)(ws + O_WFCP);
    float*  Wi0p = (float*)(ws + O_WI0P);
    float*  b1p  = (float*)(ws + O_B1P);
    char*   flg  = (char*)(ws + O_FLG);
    __bf16* bufA = (__bf16*)(ws + O_BA);
    __bf16* bufB = (__bf16*)(ws + O_BB);

    // zero flags + bufA slot0 (contiguous), and bufB slot0
    hipMemsetAsync(ws + O_FLG, 0, 2048u + 1048576u, stream);
    hipMemsetAsync(ws + O_BB, 0, 1048576u, stream);

    prep_w0   <<<4096, 256, 0, stream>>>(Wh0, W0p);
    prep_w1   <<<8192, 256, 0, stream>>>(Wi1, Wh1, W1p);
    prep_wfc  <<<768,  256, 0, stream>>>(Wfc, Wfcp);
    prep_small<<<16,   256, 0, stream>>>(Wi0, b0, b1, Wi0p, b1p);

    lstm_persist<<<256, 512, 0, stream>>>(x, W0p, W1p, Wfcp, Wi0p, b1p, bfc,
                                          bufA, bufB, flg, out);
}